// Round 1
// baseline (278.378 us; speedup 1.0000x reference)
//
#include <hip/hip_runtime.h>
#include <hip/hip_bf16.h>
#include <stdint.h>

#define NE 40000
#define FD 768
#define ED 256
#define NB 32
#define OUTC (NE + 1)

typedef __bf16 bf16x8 __attribute__((ext_vector_type(8)));
typedef float f32x4 __attribute__((ext_vector_type(4)));
typedef float f32x16 __attribute__((ext_vector_type(16)));
typedef _Float16 f16x2 __attribute__((ext_vector_type(2)));
typedef _Float16 f16x4 __attribute__((ext_vector_type(4)));

// ws layout: [0,16K) qh f16[32][256] ; [32K,96K) n01_raw fp32[64][256] ;
//            [96K,480K) Wf bf16 fragment-order [8 waves][48 chunks][64 lanes][8]
#define WS_QS 0
#define WS_N01 (32 * 1024)
#define WS_WB (96 * 1024)

__device__ __forceinline__ f16x2 pabs2(f16x2 d) {
    union { f16x2 h; unsigned u; } v; v.h = d; v.u &= 0x7FFF7FFFu; return v.h;
}

// ---------------------------------------------------------------------------
// Kprep: blocks 0..95 repack proj_W fp32 -> bf16 in per-wave MFMA fragment
// order (so gemm's B loads are 16B/lane coalesced). Blocks 96..159 project
// one query slot each (raw fp32 dot, 256 dims x K=768).
// Fragment f = ((w*48 + g)*64 + l): value = W[32w + (l&31)][g*16 + (l>>5)*8 + e]
// ---------------------------------------------------------------------------
__global__ __launch_bounds__(256) void prep_kernel(
    const float* __restrict__ ent_pkl, const float* __restrict__ W,
    const int* __restrict__ ids, const int* __restrict__ mpos,
    __bf16* __restrict__ Wf, float* __restrict__ n01_raw)
{
    const int bid = blockIdx.x;
    const int t = threadIdx.x;

    if (bid < 96) {  // wcvt: 96 blocks x 256 fragments
        const int f = bid * 256 + t;
        const int w = f / 3072;            // col-strip (wave) 0..7
        const int r = f - w * 3072;
        const int g = r >> 6;              // k-chunk 0..47
        const int l = r & 63;              // lane
        const float* src = W + (size_t)(32 * w + (l & 31)) * FD + g * 16 + (l >> 5) * 8;
        float4 a = *(const float4*)src;
        float4 b = *(const float4*)(src + 4);
        bf16x8 v;
        v[0] = (__bf16)a.x; v[1] = (__bf16)a.y; v[2] = (__bf16)a.z; v[3] = (__bf16)a.w;
        v[4] = (__bf16)b.x; v[5] = (__bf16)b.y; v[6] = (__bf16)b.z; v[7] = (__bf16)b.w;
        *(bf16x8*)(Wf + (size_t)f * 8) = v;
        return;
    }

    __shared__ float row[FD];
    const int slot = bid - 96;          // 0..63 = b*2+s
    const int b = slot >> 1, s = slot & 1;
    const int mp = mpos[0];
    const int col = (s < mp) ? s : s + 1;
    const bool wide = (ids[1] == 0 && ids[3] == 0 && ids[5] == 0);
    const int flat = b * 3 + col;
    const int idx = wide ? ids[flat * 2] : ids[flat];
    if (!(idx >= 1 && idx <= NE)) return;  // non-entity handled in qsum

    const float* src = ent_pkl + (size_t)(idx - 1) * FD;
    for (int k = t; k < FD; k += 256) row[k] = src[k];
    __syncthreads();

    const float4* w4 = (const float4*)(W + (size_t)t * FD);
    const float4* r4 = (const float4*)row;
    float a0 = 0.f, a1 = 0.f, a2 = 0.f, a3 = 0.f;
#pragma unroll 2
    for (int k4 = 0; k4 < FD / 4; k4 += 4) {
        float4 w0 = w4[k4 + 0], r0 = r4[k4 + 0];
        float4 w1 = w4[k4 + 1], r1 = r4[k4 + 1];
        float4 w2 = w4[k4 + 2], r2 = r4[k4 + 2];
        float4 w3 = w4[k4 + 3], r3 = r4[k4 + 3];
        a0 += w0.x * r0.x + w0.y * r0.y + w0.z * r0.z + w0.w * r0.w;
        a1 += w1.x * r1.x + w1.y * r1.y + w1.z * r1.z + w1.w * r1.w;
        a2 += w2.x * r2.x + w2.y * r2.y + w2.z * r2.z + w2.w * r2.w;
        a3 += w3.x * r3.x + w3.y * r3.y + w3.z * r3.z + w3.w * r3.w;
    }
    n01_raw[slot * ED + t] = (a0 + a1) + (a2 + a3);
}

// ---------------------------------------------------------------------------
// K1b: per-slot normalize, q = sum of 2 normalized rows -> qh (f16), score col 0.
// ---------------------------------------------------------------------------
__global__ __launch_bounds__(256) void qsum_kernel(
    const float* __restrict__ other_emb, const float* __restrict__ n01_raw,
    const int* __restrict__ ids, const int* __restrict__ mpos,
    _Float16* __restrict__ qh, float* __restrict__ out)
{
    __shared__ float red[4];
    __shared__ float nshare;
    const int b = blockIdx.x, t = threadIdx.x;
    const int mp = mpos[0];
    const bool wide = (ids[1] == 0 && ids[3] == 0 && ids[5] == 0);

    float q = 0.f;
#pragma unroll
    for (int s = 0; s < 2; ++s) {
        const int col = (s < mp) ? s : s + 1;
        const int flat = b * 3 + col;
        const int idx = wide ? ids[flat * 2] : ids[flat];
        float v;
        if (idx >= 1 && idx <= NE) v = n01_raw[(b * 2 + s) * ED + t];
        else if (idx == 0) v = other_emb[t];
        else v = other_emb[(size_t)(idx - NE) * ED + t];

        float ss = v * v;
#pragma unroll
        for (int o = 32; o > 0; o >>= 1) ss += __shfl_down(ss, o, 64);
        if ((t & 63) == 0) red[t >> 6] = ss;
        __syncthreads();
        if (t == 0) nshare = fmaxf(sqrtf(red[0] + red[1] + red[2] + red[3]), 1e-12f);
        __syncthreads();
        q += v / nshare;
        __syncthreads();
    }
    qh[b * ED + t] = (_Float16)q;

    float d = fabsf(q - other_emb[t]);
#pragma unroll
    for (int o = 32; o > 0; o >>= 1) d += __shfl_down(d, o, 64);
    if ((t & 63) == 0) red[t >> 6] = d;
    __syncthreads();
    if (t == 0) out[(size_t)b * OUTC] = -(red[0] + red[1] + red[2] + red[3]);
}

// ---------------------------------------------------------------------------
// K2: 625 blocks x 512 thr. Block = 64 entity rows x 256 dims.
// GEMM: mfma_f32_32x32x16_bf16; wave w owns cols 32w..32w+31, two 32-row
// strips. A staged in 2 K-halves (64x384 bf16, XOR-swizzled octets, 48 KB)
// via NON-TEMPORAL loads (stream must not evict Wf from L1/L2). B loads from
// fragment-order Wf: 16B/lane fully coalesced. C -> S f16[64][260] (row
// stride 520 B = 8-aligned, bank-balanced). Scoring: lane = entity, wave =
// 4 batches (wave-uniform q, f16); packed f16 |q-x| with f32 flush every 8
// chunks. NT stores, 256 B coalesced runs per batch. No atomics.
// ---------------------------------------------------------------------------
#define SP 260   // f16 per S row (row stride 520 B = 8*65: aligned + spread)

__global__ __launch_bounds__(512, 6) void gemm_score_kernel(
    const float* __restrict__ ent_pkl, const __bf16* __restrict__ Wf,
    const _Float16* __restrict__ qh, float* __restrict__ out)
{
    __shared__ __align__(16) unsigned char smem[49152];
    __bf16* Asm = (__bf16*)smem;     // [64][384] per K-half, XOR-swizzled
    _Float16* Sb = (_Float16*)smem;  // [64][260] overlay after GEMM

    const int t = threadIdx.x;
    const int l = t & 63;
    const int w = t >> 6;        // wave 0..7 -> cols 32w..32w+31
    const int m31 = l & 31;
    const int dh = l >> 5;       // k-half within octet pair
    const int e0 = blockIdx.x * 64;

    f32x16 acc0, acc1;
#pragma unroll
    for (int i = 0; i < 16; ++i) { acc0[i] = 0.f; acc1[i] = 0.f; }

    const int srow = t >> 3;      // 0..63 staging row
    const int sseg = t & 7;       // 8 segs x 48 floats
    const int ssw = srow & 7;
    const __bf16* bp = Wf + (size_t)w * 24576 + (size_t)l * 8;
    const __bf16* arow0 = Asm + m31 * 384;
    const __bf16* arow1 = Asm + (32 + m31) * 384;
    const int asw = m31 & 7;

#pragma unroll
    for (int h = 0; h < 2; ++h) {
        __syncthreads();  // prior half's A reads complete
        // ---- stage A half: 64 rows x 384 k, fp32 -> bf16, octet-swizzled,
        //      NT loads (pure stream: keep Wf resident in L1/L2) ----
        {
            const float* ap = ent_pkl + (size_t)(e0 + srow) * FD + h * 384 + sseg * 48;
            const f32x4* ap4 = (const f32x4*)ap;
            __bf16* dst = Asm + srow * 384;
#pragma unroll
            for (int j = 0; j < 6; ++j) {
                f32x4 x = __builtin_nontemporal_load(ap4 + 2 * j);
                f32x4 y = __builtin_nontemporal_load(ap4 + 2 * j + 1);
                bf16x8 v;
                v[0] = (__bf16)x[0]; v[1] = (__bf16)x[1]; v[2] = (__bf16)x[2]; v[3] = (__bf16)x[3];
                v[4] = (__bf16)y[0]; v[5] = (__bf16)y[1]; v[6] = (__bf16)y[2]; v[7] = (__bf16)y[3];
                *(bf16x8*)(dst + ((sseg * 6 + j) ^ ssw) * 8) = v;
            }
        }
        __syncthreads();
        // ---- 24 k-chunks: 1 coalesced B load + 2 A LDS reads + 2 MFMA ----
#pragma unroll 4
        for (int c = 0; c < 24; ++c) {
            bf16x8 bv = *(const bf16x8*)(bp + (size_t)(h * 24 + c) * 512);
            const int oct = (2 * c + dh) ^ asw;
            bf16x8 a0 = *(const bf16x8*)(arow0 + oct * 8);
            bf16x8 a1 = *(const bf16x8*)(arow1 + oct * 8);
            acc0 = __builtin_amdgcn_mfma_f32_32x32x16_bf16(a0, bv, acc0, 0, 0, 0);
            acc1 = __builtin_amdgcn_mfma_f32_32x32x16_bf16(a1, bv, acc1, 0, 0, 0);
        }
    }

    // ---- dump C -> S f16[64][260]; row=(reg&3)+8*(reg>>2)+4*dh, col=32w+m31
    __syncthreads();
#pragma unroll
    for (int r = 0; r < 16; ++r) {
        const int erow = (r & 3) + 8 * (r >> 2) + 4 * dh;
        Sb[erow * SP + 32 * w + m31] = (_Float16)acc0[r];
        Sb[(32 + erow) * SP + 32 * w + m31] = (_Float16)acc1[r];
    }
    __syncthreads();

    // ---- scoring: lane = entity l; wave handles batches 4*wu..4*wu+3 ----
    const int wu = __builtin_amdgcn_readfirstlane(w);
    const f16x4* q0 = (const f16x4*)(qh + (size_t)(4 * wu + 0) * ED);
    const f16x4* q1 = (const f16x4*)(qh + (size_t)(4 * wu + 1) * ED);
    const f16x4* q2 = (const f16x4*)(qh + (size_t)(4 * wu + 2) * ED);
    const f16x4* q3 = (const f16x4*)(qh + (size_t)(4 * wu + 3) * ED);
    const f16x4* xrow = (const f16x4*)(Sb + (size_t)l * SP);

    float s0 = 0.f, s1 = 0.f, s2 = 0.f, s3 = 0.f;
    for (int cb = 0; cb < 8; ++cb) {
        f16x2 t0 = {0, 0}, t1 = {0, 0}, t2 = {0, 0}, t3 = {0, 0};
#pragma unroll
        for (int ci = 0; ci < 8; ++ci) {
            const int c = cb * 8 + ci;
            f16x4 xv = xrow[c];
            f16x2 xlo = __builtin_shufflevector(xv, xv, 0, 1);
            f16x2 xhi = __builtin_shufflevector(xv, xv, 2, 3);
            f16x4 qa = q0[c], qb = q1[c], qc = q2[c], qd = q3[c];
            t0 = t0 + pabs2(__builtin_shufflevector(qa, qa, 0, 1) - xlo);
            t0 = t0 + pabs2(__builtin_shufflevector(qa, qa, 2, 3) - xhi);
            t1 = t1 + pabs2(__builtin_shufflevector(qb, qb, 0, 1) - xlo);
            t1 = t1 + pabs2(__builtin_shufflevector(qb, qb, 2, 3) - xhi);
            t2 = t2 + pabs2(__builtin_shufflevector(qc, qc, 0, 1) - xlo);
            t2 = t2 + pabs2(__builtin_shufflevector(qc, qc, 2, 3) - xhi);
            t3 = t3 + pabs2(__builtin_shufflevector(qd, qd, 0, 1) - xlo);
            t3 = t3 + pabs2(__builtin_shufflevector(qd, qd, 2, 3) - xhi);
        }
        s0 += (float)t0[0] + (float)t0[1];
        s1 += (float)t1[0] + (float)t1[1];
        s2 += (float)t2[0] + (float)t2[1];
        s3 += (float)t3[0] + (float)t3[1];
    }
    float* ob = out + 1 + e0 + l;
    __builtin_nontemporal_store(-s0, ob + (size_t)(4 * wu + 0) * OUTC);
    __builtin_nontemporal_store(-s1, ob + (size_t)(4 * wu + 1) * OUTC);
    __builtin_nontemporal_store(-s2, ob + (size_t)(4 * wu + 2) * OUTC);
    __builtin_nontemporal_store(-s3, ob + (size_t)(4 * wu + 3) * OUTC);
}

extern "C" void kernel_launch(void* const* d_in, const int* in_sizes, int n_in,
                              void* d_out, int out_size, void* d_ws, size_t ws_size,
                              hipStream_t stream) {
    const float* ent_pkl = (const float*)d_in[0];
    const float* other_emb = (const float*)d_in[1];
    const float* proj_W = (const float*)d_in[2];
    const int* ids = (const int*)d_in[3];
    const int* mpos = (const int*)d_in[4];
    float* out = (float*)d_out;

    _Float16* qh = (_Float16*)((char*)d_ws + WS_QS);
    float* n01_raw = (float*)((char*)d_ws + WS_N01);
    __bf16* Wf = (__bf16*)((char*)d_ws + WS_WB);

    prep_kernel<<<160, 256, 0, stream>>>(ent_pkl, proj_W, ids, mpos, Wf, n01_raw);
    qsum_kernel<<<NB, 256, 0, stream>>>(other_emb, n01_raw, ids, mpos, qh, out);
    gemm_score_kernel<<<NE / 64, 512, 0, stream>>>(ent_pkl, Wf, qh, out);
}

// Round 2
// 245.393 us; speedup vs baseline: 1.1344x; 1.1344x over previous
//
#include <hip/hip_runtime.h>
#include <hip/hip_bf16.h>
#include <stdint.h>

#define NE 40000
#define FD 768
#define ED 256
#define NB 32
#define OUTC (NE + 1)

typedef __bf16 bf16x8 __attribute__((ext_vector_type(8)));
typedef float f32x4 __attribute__((ext_vector_type(4)));
typedef float f32x16 __attribute__((ext_vector_type(16)));
typedef _Float16 f16x2 __attribute__((ext_vector_type(2)));
typedef _Float16 f16x4 __attribute__((ext_vector_type(4)));

// ws layout: [0,16K) qh f16[32][256] ; [32K,96K) n01_raw fp32[64][256] ;
//            [96K,480K) Wf bf16 fragment-order [8 waves][48 chunks][64 lanes][8]
#define WS_QS 0
#define WS_N01 (32 * 1024)
#define WS_WB (96 * 1024)

__device__ __forceinline__ f16x2 pabs2(f16x2 d) {
    union { f16x2 h; unsigned u; } v; v.h = d; v.u &= 0x7FFF7FFFu; return v.h;
}

// async global->LDS DMA, 16B per lane, zero VGPR cost (full MLP)
__device__ __forceinline__ void gload16(const void* g, void* l) {
    __builtin_amdgcn_global_load_lds(
        (const __attribute__((address_space(1))) unsigned int*)g,
        (__attribute__((address_space(3))) unsigned int*)l, 16, 0, 0);
}

// ---------------------------------------------------------------------------
// Kprep: blocks 0..191 convert proj_W fp32->bf16, COALESCED read + scattered
// 8B write into MFMA fragment order. Blocks 192..447: projection, 4 blocks
// per slot; wave-per-output-row, lanes sweep K coalesced, shfl_xor reduce.
// Fragment f = ((w*48+g)*64+l): value = W[32w + (l&31)][16g + 8*(l>>5) + e]
// ---------------------------------------------------------------------------
__global__ __launch_bounds__(256) void prep_kernel(
    const float* __restrict__ ent_pkl, const float* __restrict__ W,
    const int* __restrict__ ids, const int* __restrict__ mpos,
    __bf16* __restrict__ Wf, float* __restrict__ n01_raw)
{
    __shared__ f32x4 xs4[FD / 4];
    const int bid = blockIdx.x;
    const int t = threadIdx.x;

    if (bid < 192) {  // wcvt: linear read, fragment-scatter write
        const int i = bid * 1024 + t * 4;
        const int r = i / FD, c = i - r * FD;
        float4 v = *(const float4*)(W + i);
        __bf16 o[4] = {(__bf16)v.x, (__bf16)v.y, (__bf16)v.z, (__bf16)v.w};
        const int f = ((r >> 5) * 48 + (c >> 4)) * 64 + (r & 31) + ((c >> 3) & 1) * 32;
        *(ushort4*)(Wf + (size_t)f * 8 + (c & 7)) = *(const ushort4*)o;
        return;
    }

    // projection: sub block = (slot, output-quarter)
    const int sub = bid - 192;           // 0..255
    const int slot = sub >> 2;           // 0..63 = b*2+s
    const int oq = sub & 3;              // output rows [oq*64, oq*64+64)
    const int b = slot >> 1, s = slot & 1;
    const int mp = mpos[0];
    const int col = (s < mp) ? s : s + 1;
    const bool wide = (ids[1] == 0 && ids[3] == 0 && ids[5] == 0);
    const int flat = b * 3 + col;
    const int idx = wide ? ids[flat * 2] : ids[flat];
    if (!(idx >= 1 && idx <= NE)) return;  // non-entity handled in qsum

    if (t < FD / 4) xs4[t] = ((const f32x4*)(ent_pkl + (size_t)(idx - 1) * FD))[t];
    __syncthreads();

    const int l = t & 63, wv = t >> 6;
    const f32x4 x0 = xs4[l], x1 = xs4[l + 64], x2 = xs4[l + 128];
    const int obase = oq * 64 + wv * 16;
#pragma unroll 2
    for (int i = 0; i < 16; ++i) {
        const int o = obase + i;
        const f32x4* wr = (const f32x4*)(W + (size_t)o * FD);
        f32x4 w0 = wr[l], w1 = wr[l + 64], w2 = wr[l + 128];
        float p = w0[0] * x0[0] + w0[1] * x0[1] + w0[2] * x0[2] + w0[3] * x0[3]
                + w1[0] * x1[0] + w1[1] * x1[1] + w1[2] * x1[2] + w1[3] * x1[3]
                + w2[0] * x2[0] + w2[1] * x2[1] + w2[2] * x2[2] + w2[3] * x2[3];
#pragma unroll
        for (int off = 32; off; off >>= 1) p += __shfl_xor(p, off, 64);
        if (l == 0) n01_raw[slot * ED + o] = p;
    }
}

// ---------------------------------------------------------------------------
// K1b: per-slot normalize, q = sum of 2 normalized rows -> qh (f16), score col 0.
// ---------------------------------------------------------------------------
__global__ __launch_bounds__(256) void qsum_kernel(
    const float* __restrict__ other_emb, const float* __restrict__ n01_raw,
    const int* __restrict__ ids, const int* __restrict__ mpos,
    _Float16* __restrict__ qh, float* __restrict__ out)
{
    __shared__ float red[4];
    __shared__ float nshare;
    const int b = blockIdx.x, t = threadIdx.x;
    const int mp = mpos[0];
    const bool wide = (ids[1] == 0 && ids[3] == 0 && ids[5] == 0);

    float q = 0.f;
#pragma unroll
    for (int s = 0; s < 2; ++s) {
        const int col = (s < mp) ? s : s + 1;
        const int flat = b * 3 + col;
        const int idx = wide ? ids[flat * 2] : ids[flat];
        float v;
        if (idx >= 1 && idx <= NE) v = n01_raw[(b * 2 + s) * ED + t];
        else if (idx == 0) v = other_emb[t];
        else v = other_emb[(size_t)(idx - NE) * ED + t];

        float ss = v * v;
#pragma unroll
        for (int o = 32; o > 0; o >>= 1) ss += __shfl_down(ss, o, 64);
        if ((t & 63) == 0) red[t >> 6] = ss;
        __syncthreads();
        if (t == 0) nshare = fmaxf(sqrtf(red[0] + red[1] + red[2] + red[3]), 1e-12f);
        __syncthreads();
        q += v / nshare;
        __syncthreads();
    }
    qh[b * ED + t] = (_Float16)q;

    float d = fabsf(q - other_emb[t]);
#pragma unroll
    for (int o = 32; o > 0; o >>= 1) d += __shfl_down(d, o, 64);
    if ((t & 63) == 0) red[t >> 6] = d;
    __syncthreads();
    if (t == 0) out[(size_t)b * OUTC] = -(red[0] + red[1] + red[2] + red[3]);
}

// ---------------------------------------------------------------------------
// K2: 625 blocks x 512 thr. Block = 64 entity rows x 256 dims.
// A staged as FP32 via global_load_lds in 4 K-quarters (64x192 f32 = 48 KB),
// 16B-unit XOR swizzle applied on the GLOBAL source address (gld dest is
// linear). GEMM reads 2x ds_read_b128 f32 per fragment, converts to bf16 in
// regs (cvt_pk), mfma_f32_32x32x16_bf16; wave w owns cols 32w..32w+31.
// C -> S f16[64][256] with granule swizzle phys = c ^ (row&15) (b64 reads at
// the 4/bank floor). q table (32x256 f16, 16 KB) copied to LDS; scoring q
// reads are same-address broadcasts. Stores NT, 256 B coalesced runs.
// ---------------------------------------------------------------------------
#define SP 256

__global__ __launch_bounds__(512, 6) void gemm_score_kernel(
    const float* __restrict__ ent_pkl, const __bf16* __restrict__ Wf,
    const _Float16* __restrict__ qh, float* __restrict__ out)
{
    __shared__ __align__(16) unsigned char smem[49152];
    float* Af = (float*)smem;            // [64][192] f32 per quarter (swizzled units)
    _Float16* Sb = (_Float16*)smem;      // [64][256] overlay after GEMM
    _Float16* qL = (_Float16*)(smem + 32768);  // [32][256] f16 q table

    const int t = threadIdx.x;
    const int l = t & 63;
    const int w = t >> 6;        // wave 0..7 -> cols 32w..32w+31
    const int m31 = l & 31;
    const int dh = l >> 5;       // k-half within chunk
    const int e0 = blockIdx.x * 64;

    f32x16 acc0, acc1;
#pragma unroll
    for (int i = 0; i < 16; ++i) { acc0[i] = 0.f; acc1[i] = 0.f; }

    // staging address precompute (quarter-invariant): phys 16B unit p = j*512+t
    // holds logical unit lc = pc ^ (row&7) of row = p/48  (involution)
    int srow[6], slc[6];
#pragma unroll
    for (int j = 0; j < 6; ++j) {
        const int p = j * 512 + t;
        const int r = p / 48;
        srow[j] = r;
        slc[j] = (p - r * 48) ^ (r & 7);
    }

    const __bf16* bp = Wf + (size_t)w * 24576 + (size_t)l * 8;
    const int sw = m31 & 7;
    const float* a0base = Af + m31 * 192;
    const float* a1base = Af + (32 + m31) * 192;

    for (int q = 0; q < 4; ++q) {
        __syncthreads();   // prior quarter's A reads complete before DMA overwrite
#pragma unroll
        for (int j = 0; j < 6; ++j) {
            gload16(ent_pkl + (size_t)(e0 + srow[j]) * FD + q * 192 + slc[j] * 4,
                    (float*)smem + (size_t)(j * 512 + t) * 4);
        }
        __syncthreads();   // drains vmcnt: DMA landed
        const __bf16* bq = bp + (size_t)q * 12 * 512;
#pragma unroll 4
        for (int c = 0; c < 12; ++c) {
            bf16x8 bv = *(const bf16x8*)(bq + c * 512);
            const int u0 = 4 * c + 2 * dh;
            const int p0 = (u0 ^ sw) * 4, p1 = ((u0 + 1) ^ sw) * 4;
            f32x4 lo0 = *(const f32x4*)(a0base + p0);
            f32x4 hi0 = *(const f32x4*)(a0base + p1);
            f32x4 lo1 = *(const f32x4*)(a1base + p0);
            f32x4 hi1 = *(const f32x4*)(a1base + p1);
            bf16x8 a0, a1;
            a0[0] = (__bf16)lo0[0]; a0[1] = (__bf16)lo0[1]; a0[2] = (__bf16)lo0[2]; a0[3] = (__bf16)lo0[3];
            a0[4] = (__bf16)hi0[0]; a0[5] = (__bf16)hi0[1]; a0[6] = (__bf16)hi0[2]; a0[7] = (__bf16)hi0[3];
            a1[0] = (__bf16)lo1[0]; a1[1] = (__bf16)lo1[1]; a1[2] = (__bf16)lo1[2]; a1[3] = (__bf16)lo1[3];
            a1[4] = (__bf16)hi1[0]; a1[5] = (__bf16)hi1[1]; a1[6] = (__bf16)hi1[2]; a1[7] = (__bf16)hi1[3];
            acc0 = __builtin_amdgcn_mfma_f32_32x32x16_bf16(a0, bv, acc0, 0, 0, 0);
            acc1 = __builtin_amdgcn_mfma_f32_32x32x16_bf16(a1, bv, acc1, 0, 0, 0);
        }
    }

    // ---- dump C -> S f16[64][256]; row=(reg&3)+8*(reg>>2)+4*dh, col=32w+m31,
    //      granule-swizzled: phys granule = (col>>2) ^ (row&15)
    __syncthreads();
    const int colg = 8 * w + (m31 >> 2);
    const int csub = m31 & 3;
#pragma unroll
    for (int r = 0; r < 16; ++r) {
        const int erow = (r & 3) + 8 * (r >> 2) + 4 * dh;
        const int ph = (((colg ^ (erow & 15)) << 2) | csub);
        Sb[erow * SP + ph] = (_Float16)acc0[r];
        Sb[(32 + erow) * SP + ph] = (_Float16)acc1[r];   // (32+erow)&15 == erow&15
    }
    // ---- q table -> LDS (16 KB, 2x 16B per thread) ----
    {
        const uint4* qsrc = (const uint4*)qh;
        uint4* qdst = (uint4*)qL;
        qdst[t] = qsrc[t];
        qdst[t + 512] = qsrc[t + 512];
    }
    __syncthreads();

    // ---- scoring: lane = entity l; wave handles batches 4*wu..4*wu+3 ----
    const int wu = __builtin_amdgcn_readfirstlane(w);
    const f16x4* q0 = (const f16x4*)(qL + (size_t)(4 * wu + 0) * ED);
    const f16x4* q1 = (const f16x4*)(qL + (size_t)(4 * wu + 1) * ED);
    const f16x4* q2 = (const f16x4*)(qL + (size_t)(4 * wu + 2) * ED);
    const f16x4* q3 = (const f16x4*)(qL + (size_t)(4 * wu + 3) * ED);
    const int swl = l & 15;
    const _Float16* xbase = Sb + (size_t)l * SP;

    float s0 = 0.f, s1 = 0.f, s2 = 0.f, s3 = 0.f;
    for (int cb = 0; cb < 8; ++cb) {
        f16x2 t0 = {0, 0}, t1 = {0, 0}, t2 = {0, 0}, t3 = {0, 0};
#pragma unroll
        for (int ci = 0; ci < 8; ++ci) {
            const int c = cb * 8 + ci;
            f16x4 xv = *(const f16x4*)(xbase + ((c ^ swl) << 2));
            f16x2 xlo = __builtin_shufflevector(xv, xv, 0, 1);
            f16x2 xhi = __builtin_shufflevector(xv, xv, 2, 3);
            f16x4 qa = q0[c], qb = q1[c], qc = q2[c], qd = q3[c];
            t0 = t0 + pabs2(__builtin_shufflevector(qa, qa, 0, 1) - xlo);
            t0 = t0 + pabs2(__builtin_shufflevector(qa, qa, 2, 3) - xhi);
            t1 = t1 + pabs2(__builtin_shufflevector(qb, qb, 0, 1) - xlo);
            t1 = t1 + pabs2(__builtin_shufflevector(qb, qb, 2, 3) - xhi);
            t2 = t2 + pabs2(__builtin_shufflevector(qc, qc, 0, 1) - xlo);
            t2 = t2 + pabs2(__builtin_shufflevector(qc, qc, 2, 3) - xhi);
            t3 = t3 + pabs2(__builtin_shufflevector(qd, qd, 0, 1) - xlo);
            t3 = t3 + pabs2(__builtin_shufflevector(qd, qd, 2, 3) - xhi);
        }
        s0 += (float)t0[0] + (float)t0[1];
        s1 += (float)t1[0] + (float)t1[1];
        s2 += (float)t2[0] + (float)t2[1];
        s3 += (float)t3[0] + (float)t3[1];
    }
    float* ob = out + 1 + e0 + l;
    __builtin_nontemporal_store(-s0, ob + (size_t)(4 * wu + 0) * OUTC);
    __builtin_nontemporal_store(-s1, ob + (size_t)(4 * wu + 1) * OUTC);
    __builtin_nontemporal_store(-s2, ob + (size_t)(4 * wu + 2) * OUTC);
    __builtin_nontemporal_store(-s3, ob + (size_t)(4 * wu + 3) * OUTC);
}

extern "C" void kernel_launch(void* const* d_in, const int* in_sizes, int n_in,
                              void* d_out, int out_size, void* d_ws, size_t ws_size,
                              hipStream_t stream) {
    const float* ent_pkl = (const float*)d_in[0];
    const float* other_emb = (const float*)d_in[1];
    const float* proj_W = (const float*)d_in[2];
    const int* ids = (const int*)d_in[3];
    const int* mpos = (const int*)d_in[4];
    float* out = (float*)d_out;

    _Float16* qh = (_Float16*)((char*)d_ws + WS_QS);
    float* n01_raw = (float*)((char*)d_ws + WS_N01);
    __bf16* Wf = (__bf16*)((char*)d_ws + WS_WB);

    prep_kernel<<<448, 256, 0, stream>>>(ent_pkl, proj_W, ids, mpos, Wf, n01_raw);
    qsum_kernel<<<NB, 256, 0, stream>>>(other_emb, n01_raw, ids, mpos, qh, out);
    gemm_score_kernel<<<NE / 64, 512, 0, stream>>>(ent_pkl, Wf, qh, out);
}